// Round 1
// baseline (158.440 us; speedup 1.0000x reference)
//
#include <hip/hip_runtime.h>

#define C_IN 256
#define C_MID 64
#define HH 56
#define WW 56
#define HWSZ 3136
#define KS 7
#define KK 49
#define NG 16
#define GCH 16

// ---------------- Kernel A: t[bhw][64] = relu(BN(w1 @ x)) ----------------
// grid 392 = 49 position-chunks x 8 o-chunks, block 256
__global__ __launch_bounds__(256) void ka_tmid(
    const float* __restrict__ x, const float* __restrict__ w1,
    const float* __restrict__ gamma, const float* __restrict__ beta,
    const float* __restrict__ mean, const float* __restrict__ var,
    float* __restrict__ t_ws)
{
    __shared__ __align__(16) float w1s[8 * 256];
    const int oc = blockIdx.x & 7;
    const int pc = blockIdx.x >> 3;
    const int o0 = oc * 8;
    const int tid = threadIdx.x;

    for (int i = tid; i < 8 * 256; i += 256)
        w1s[i] = w1[o0 * 256 + i];
    __syncthreads();

    const int p = pc * 256 + tid;           // global bhw index, 0..12544
    const int b = p / HWSZ;
    const int hw = p - b * HWSZ;
    const float* xp = x + (size_t)b * C_IN * HWSZ + hw;

    float acc[8] = {0.f,0.f,0.f,0.f,0.f,0.f,0.f,0.f};
    #pragma unroll 4
    for (int c0 = 0; c0 < C_IN; c0 += 4) {
        float xv0 = xp[(size_t)(c0 + 0) * HWSZ];
        float xv1 = xp[(size_t)(c0 + 1) * HWSZ];
        float xv2 = xp[(size_t)(c0 + 2) * HWSZ];
        float xv3 = xp[(size_t)(c0 + 3) * HWSZ];
        #pragma unroll
        for (int j = 0; j < 8; ++j) {
            float4 wv = *(const float4*)&w1s[j * 256 + c0];
            acc[j] += wv.x * xv0 + wv.y * xv1 + wv.z * xv2 + wv.w * xv3;
        }
    }

    float res[8];
    #pragma unroll
    for (int j = 0; j < 8; ++j) {
        int o = o0 + j;
        float sc = gamma[o] * rsqrtf(var[o] + 1e-5f);
        float sh = beta[o] - mean[o] * sc;
        float v = acc[j] * sc + sh;
        res[j] = v > 0.f ? v : 0.f;
    }
    float* tp = t_ws + (size_t)p * 64 + o0;
    *(float4*)&tp[0] = make_float4(res[0], res[1], res[2], res[3]);
    *(float4*)&tp[4] = make_float4(res[4], res[5], res[6], res[7]);
}

// ------- Kernel B: fused weight-GEMM + dynamic conv, one (b,h) row -------
// grid 448 = 4 b x 56 h x 2 group-halves, block 256
__global__ __launch_bounds__(256) void kb_fused(
    const float* __restrict__ y, const float* __restrict__ w2,
    const float* __restrict__ b2, const float* __restrict__ t_ws,
    float* __restrict__ out)
{
    __shared__ __align__(16) float t_lds[64 * 60];    // [c][w] stride 60
    __shared__ __align__(16) float w2_lds[52 * 66];   // [ol][c] stride 66
    __shared__ __align__(16) float wgt_lds[52 * 60];  // [kk][w] stride 60
    __shared__ __align__(16) float y_lds[16 * 7 * 64];// [cc][dr][col], col = w+3

    const int tid = threadIdx.x;
    const int blk = blockIdx.x;
    const int b = blk / 112;
    const int rest = blk - b * 112;
    const int h = rest >> 1;
    const int g0 = (rest & 1) * 8;

    // stage t tile: 56 positions x 64 channels -> t_lds[c][w]
    const float* tsrc = t_ws + ((size_t)b * HWSZ + (size_t)h * WW) * 64;
    for (int i = tid; i < WW * 64; i += 256) {
        int w = i >> 6, c = i & 63;
        t_lds[c * 60 + w] = tsrc[i];
    }

    for (int g = g0; g < g0 + 8; ++g) {
        __syncthreads();  // protects w2/y/wgt reuse across g (and t on first iter below)

        // stage w2 group slice (zero-pad rows 49..51)
        for (int i = tid; i < 52 * 64; i += 256) {
            int ol = i >> 6, c = i & 63;
            w2_lds[ol * 66 + c] = (ol < KK) ? w2[(g * KK + ol) * 64 + c] : 0.f;
        }
        // stage y halo: rows h-3..h+3, cols -3..60 (zero outside)
        for (int i = tid; i < 16 * 7 * 64; i += 256) {
            int cc = i / 448;
            int r = i - cc * 448;
            int dr = r >> 6, col = r & 63;
            int hs = h - 3 + dr, ws = col - 3;
            float v = 0.f;
            if ((unsigned)hs < HH && (unsigned)ws < WW)
                v = y[((size_t)(b * C_IN + g * GCH + cc) * HH + hs) * WW + ws];
            y_lds[i] = v;
        }
        __syncthreads();

        // GEMM: wgt[ol][w] = b2[g*49+ol] + sum_c w2[ol][c] * t[c][w]
        {
            const int oq = tid >> 4, pq = tid & 15;
            if (oq < 13 && pq < 14) {
                float acc[4][4];
                #pragma unroll
                for (int i = 0; i < 4; ++i) {
                    int ol = oq * 4 + i;
                    float bv = (ol < KK) ? b2[g * KK + ol] : 0.f;
                    #pragma unroll
                    for (int j = 0; j < 4; ++j) acc[i][j] = bv;
                }
                for (int c = 0; c < 64; ++c) {
                    float4 tv = *(const float4*)&t_lds[c * 60 + pq * 4];
                    #pragma unroll
                    for (int i = 0; i < 4; ++i) {
                        float wv = w2_lds[(oq * 4 + i) * 66 + c];
                        acc[i][0] += wv * tv.x; acc[i][1] += wv * tv.y;
                        acc[i][2] += wv * tv.z; acc[i][3] += wv * tv.w;
                    }
                }
                #pragma unroll
                for (int i = 0; i < 4; ++i) {
                    int ol = oq * 4 + i;
                    if (ol < KK)
                        *(float4*)&wgt_lds[ol * 60 + pq * 4] =
                            make_float4(acc[i][0], acc[i][1], acc[i][2], acc[i][3]);
                }
            }
        }
        __syncthreads();

        // conv: out[cc][w] = sum_{di,dj} wgt[di*7+dj][w] * y[cc][h+di-3][w+dj-3]
        {
            const int cc = tid >> 4, pq = tid & 15;
            if (pq < 14) {
                float a0 = 0.f, a1 = 0.f, a2 = 0.f, a3 = 0.f;
                #pragma unroll
                for (int di = 0; di < KS; ++di) {
                    const float* yrow = &y_lds[(cc * 7 + di) * 64 + pq * 4];
                    float4 yq0 = *(const float4*)&yrow[0];
                    float4 yq1 = *(const float4*)&yrow[4];
                    float4 yq2 = *(const float4*)&yrow[8];
                    float yv[12] = {yq0.x, yq0.y, yq0.z, yq0.w,
                                    yq1.x, yq1.y, yq1.z, yq1.w,
                                    yq2.x, yq2.y, yq2.z, yq2.w};
                    #pragma unroll
                    for (int dj = 0; dj < KS; ++dj) {
                        float4 wv = *(const float4*)&wgt_lds[(di * 7 + dj) * 60 + pq * 4];
                        a0 += wv.x * yv[dj + 0];
                        a1 += wv.y * yv[dj + 1];
                        a2 += wv.z * yv[dj + 2];
                        a3 += wv.w * yv[dj + 3];
                    }
                }
                float* op = out + ((size_t)(b * C_IN) + g * GCH + cc) * HWSZ
                            + (size_t)h * WW + pq * 4;
                *(float4*)op = make_float4(a0, a1, a2, a3);
            }
        }
    }
}

extern "C" void kernel_launch(void* const* d_in, const int* in_sizes, int n_in,
                              void* d_out, int out_size, void* d_ws, size_t ws_size,
                              hipStream_t stream) {
    const float* x     = (const float*)d_in[0];
    const float* y     = (const float*)d_in[1];
    const float* w1    = (const float*)d_in[2];
    const float* gamma = (const float*)d_in[3];
    const float* beta  = (const float*)d_in[4];
    const float* mean  = (const float*)d_in[5];
    const float* var   = (const float*)d_in[6];
    const float* w2    = (const float*)d_in[7];
    const float* b2    = (const float*)d_in[8];
    float* out  = (float*)d_out;
    float* t_ws = (float*)d_ws;   // 4*3136*64 floats = 3.2 MB

    ka_tmid<<<392, 256, 0, stream>>>(x, w1, gamma, beta, mean, var, t_ws);
    kb_fused<<<448, 256, 0, stream>>>(y, w2, b2, t_ws, out);
}

// Round 2
// 83.140 us; speedup vs baseline: 1.9057x; 1.9057x over previous
//
#include <hip/hip_runtime.h>

#define HH 56
#define WW 56
#define HWSZ 3136
#define KS 7
#define KK 49

typedef __attribute__((ext_vector_type(8))) short short8;
typedef __attribute__((ext_vector_type(4))) float f32x4;

__device__ inline unsigned short f2bf(float f) {
    unsigned u = __builtin_bit_cast(unsigned, f);
    u += 0x7FFF + ((u >> 16) & 1);          // RNE
    return (unsigned short)(u >> 16);
}

// --------- Kernel A: t[p][64] = relu(BN(w1@x)) in bf16, + w2->bf16 prep ---------
// grid 392 (=196 p-chunks x 2 o-halves) + 16 prep blocks, block 256
__global__ __launch_bounds__(256) void ka_tmid(
    const float* __restrict__ x, const float* __restrict__ w1,
    const float* __restrict__ gamma, const float* __restrict__ beta,
    const float* __restrict__ mean, const float* __restrict__ var,
    const float* __restrict__ w2,
    unsigned short* __restrict__ t_bf, unsigned short* __restrict__ w2p)
{
    const int tid = threadIdx.x;
    if (blockIdx.x >= 392) {
        // w2 prep: one block per group g; pad rows 49..63 with zeros
        const int g = blockIdx.x - 392;
        for (int i = tid; i < 64 * 64; i += 256) {
            int r = i >> 6, k = i & 63;
            float v = (r < KK) ? w2[(g * KK + r) * 64 + k] : 0.f;
            w2p[(size_t)(g * 64 + r) * 64 + k] = f2bf(v);
        }
        return;
    }
    __shared__ __align__(16) float w1s[32 * 256];
    const int oc = blockIdx.x & 1;          // which 32 output channels
    const int pc = blockIdx.x >> 1;         // 64-pixel chunk
    for (int i = tid; i < 32 * 256; i += 256)
        w1s[i] = w1[oc * 32 * 256 + i];
    __syncthreads();

    const int pix = tid & 63, osel = tid >> 6;   // 4 waves = 4 output-octets
    const int p = pc * 64 + pix;
    const int b = p / HWSZ, hw = p - b * HWSZ;
    const float* xp = x + (size_t)b * 256 * HWSZ + hw;

    float acc[8] = {0.f,0.f,0.f,0.f,0.f,0.f,0.f,0.f};
    #pragma unroll 4
    for (int c0 = 0; c0 < 256; c0 += 4) {
        float xv0 = xp[(size_t)(c0 + 0) * HWSZ];
        float xv1 = xp[(size_t)(c0 + 1) * HWSZ];
        float xv2 = xp[(size_t)(c0 + 2) * HWSZ];
        float xv3 = xp[(size_t)(c0 + 3) * HWSZ];
        #pragma unroll
        for (int j = 0; j < 8; ++j) {
            float4 wv = *(const float4*)&w1s[(osel * 8 + j) * 256 + c0];
            acc[j] += wv.x * xv0 + wv.y * xv1 + wv.z * xv2 + wv.w * xv3;
        }
    }
    const int o0 = oc * 32 + osel * 8;
    short8 sv;
    #pragma unroll
    for (int j = 0; j < 8; ++j) {
        int o = o0 + j;
        float sc = gamma[o] * rsqrtf(var[o] + 1e-5f);
        float sh = beta[o] - mean[o] * sc;
        float v = acc[j] * sc + sh;
        v = v > 0.f ? v : 0.f;
        sv[j] = (short)f2bf(v);
    }
    *(short8*)&t_bf[(size_t)p * 64 + o0] = sv;
}

// --------- Kernel B: MFMA weight-GEMM + dynamic conv, one (b,h,g) ---------
// grid 3584 = 4b x 56h x 16g, block 256 (4 waves)
__global__ __launch_bounds__(256) void kb_fused(
    const float* __restrict__ y, const float* __restrict__ b2,
    const unsigned short* __restrict__ t_bf, const unsigned short* __restrict__ w2p,
    float* __restrict__ out)
{
    __shared__ __align__(16) float ylds[16 * 7 * 68];  // [cc][di][col] stride 68
    __shared__ __align__(16) float wgt[64 * 68];       // [kk][pix]     stride 68

    const int tid = threadIdx.x;
    // XCD-bijective swizzle: 3584 % 8 == 0 -> contiguous 448-block chunks per XCD
    const int blk = (blockIdx.x & 7) * 448 + (blockIdx.x >> 3);
    const int b = blk / 896;
    const int r = blk - b * 896;
    const int h = r >> 4, g = r & 15;

    // ---- stage y halo: rows h-3..h+3, cols -3..60, 16 channels of group g ----
    for (int i = tid; i < 16 * 7 * 64; i += 256) {
        int cc = i / 448;
        int rr = i - cc * 448;
        int dr = rr >> 6, col = rr & 63;
        int hs = h - 3 + dr, ws = col - 3;
        float v = 0.f;
        if ((unsigned)hs < HH && (unsigned)ws < WW)
            v = y[((size_t)(b * 256 + g * 16 + cc) * HH + hs) * WW + ws];
        ylds[(cc * 7 + dr) * 68 + col] = v;
    }

    // ---- MFMA: wgt[kk][pix] = sum_k t[pix][k] * w2p[g][kk][k]  (+b2) ----
    // wave wv owns pixel tile [wv*16, wv*16+16); 4 m-tiles cover kk 0..63
    {
        const int lane = tid & 63, wv = tid >> 6;
        const int prow = b * HWSZ + h * WW + wv * 16 + (lane & 15);
        const short8* ta = (const short8*)(t_bf + (size_t)prow * 64 + ((lane >> 4) * 8));
        short8 a0 = ta[0];          // k =      (lane>>4)*8 + 0..7
        short8 a1 = ta[4];          // k = 32 + (lane>>4)*8 + 0..7
        f32x4 zero = {0.f, 0.f, 0.f, 0.f};
        f32x4 acc[4];
        #pragma unroll
        for (int mt = 0; mt < 4; ++mt) acc[mt] = zero;
        #pragma unroll
        for (int mt = 0; mt < 4; ++mt) {
            const short8* tb = (const short8*)(w2p +
                (size_t)(g * 64 + mt * 16 + (lane & 15)) * 64 + ((lane >> 4) * 8));
            short8 b0 = tb[0], b1 = tb[4];
            acc[mt] = __builtin_amdgcn_mfma_f32_16x16x32_bf16(a0, b0, acc[mt], 0, 0, 0);
            acc[mt] = __builtin_amdgcn_mfma_f32_16x16x32_bf16(a1, b1, acc[mt], 0, 0, 0);
        }
        // D layout: col(kk) = lane&15, row(pix) = (lane>>4)*4 + j
        #pragma unroll
        for (int mt = 0; mt < 4; ++mt) {
            int kk = mt * 16 + (lane & 15);
            float bv = (kk < KK) ? b2[g * KK + kk] : 0.f;
            f32x4 v = acc[mt];
            v.x += bv; v.y += bv; v.z += bv; v.w += bv;
            int pixb = wv * 16 + ((lane >> 4) << 2);
            *(f32x4*)&wgt[kk * 68 + pixb] = v;   // aligned b128
        }
    }
    __syncthreads();

    // ---- conv: out[cc][w] = sum_{di,dj} wgt[di*7+dj][w] * ylds[cc][di][w+dj] ----
    {
        const int cc = tid >> 4, pq = tid & 15;
        if (pq < 14) {
            float a0 = 0.f, a1 = 0.f, a2 = 0.f, a3 = 0.f;
            #pragma unroll
            for (int di = 0; di < KS; ++di) {
                const float* yrow = &ylds[(cc * 7 + di) * 68 + pq * 4];
                float4 yq0 = *(const float4*)&yrow[0];
                float4 yq1 = *(const float4*)&yrow[4];
                float4 yq2 = *(const float4*)&yrow[8];
                float yv[12] = {yq0.x, yq0.y, yq0.z, yq0.w,
                                yq1.x, yq1.y, yq1.z, yq1.w,
                                yq2.x, yq2.y, yq2.z, yq2.w};
                #pragma unroll
                for (int dj = 0; dj < KS; ++dj) {
                    float4 wv = *(const float4*)&wgt[(di * KS + dj) * 68 + pq * 4];
                    a0 += wv.x * yv[dj + 0];
                    a1 += wv.y * yv[dj + 1];
                    a2 += wv.z * yv[dj + 2];
                    a3 += wv.w * yv[dj + 3];
                }
            }
            float* op = out + ((size_t)(b * 256) + g * 16 + cc) * HWSZ
                        + (size_t)h * WW + pq * 4;
            *(float4*)op = make_float4(a0, a1, a2, a3);
        }
    }
}

extern "C" void kernel_launch(void* const* d_in, const int* in_sizes, int n_in,
                              void* d_out, int out_size, void* d_ws, size_t ws_size,
                              hipStream_t stream) {
    const float* x     = (const float*)d_in[0];
    const float* y     = (const float*)d_in[1];
    const float* w1    = (const float*)d_in[2];
    const float* gamma = (const float*)d_in[3];
    const float* beta  = (const float*)d_in[4];
    const float* mean  = (const float*)d_in[5];
    const float* var   = (const float*)d_in[6];
    const float* w2    = (const float*)d_in[7];
    const float* b2    = (const float*)d_in[8];
    float* out = (float*)d_out;

    // ws: t_bf [12608][64] bf16 (64 pad rows for pixel-tile overrun), then w2p [16*64][64] bf16
    unsigned short* t_bf = (unsigned short*)d_ws;
    unsigned short* w2p  = t_bf + (size_t)12608 * 64;

    ka_tmid<<<408, 256, 0, stream>>>(x, w1, gamma, beta, mean, var, w2, t_bf, w2p);
    kb_fused<<<3584, 256, 0, stream>>>(y, b2, t_bf, w2p, out);
}

// Round 3
// 74.260 us; speedup vs baseline: 2.1336x; 1.1196x over previous
//
#include <hip/hip_runtime.h>

#define HH 56
#define WW 56
#define HWSZ 3136
#define KS 7
#define KK 49

typedef __attribute__((ext_vector_type(8))) short short8;
typedef __attribute__((ext_vector_type(4))) float f32x4;

__device__ inline unsigned short f2bf(float f) {
    unsigned u = __builtin_bit_cast(unsigned, f);
    u += 0x7FFF + ((u >> 16) & 1);          // RNE
    return (unsigned short)(u >> 16);
}
__device__ inline float bflo(unsigned u) { return __builtin_bit_cast(float, u << 16); }
__device__ inline float bfhi(unsigned u) { return __builtin_bit_cast(float, u & 0xFFFF0000u); }

// --------- Kernel A: t[p][64] = relu(BN(w1@x)) in bf16, + w2->bf16 prep ---------
__global__ __launch_bounds__(256) void ka_tmid(
    const float* __restrict__ x, const float* __restrict__ w1,
    const float* __restrict__ gamma, const float* __restrict__ beta,
    const float* __restrict__ mean, const float* __restrict__ var,
    const float* __restrict__ w2,
    unsigned short* __restrict__ t_bf, unsigned short* __restrict__ w2p)
{
    const int tid = threadIdx.x;
    if (blockIdx.x >= 392) {
        const int g = blockIdx.x - 392;
        for (int i = tid; i < 64 * 64; i += 256) {
            int r = i >> 6, k = i & 63;
            float v = (r < KK) ? w2[(g * KK + r) * 64 + k] : 0.f;
            w2p[(size_t)(g * 64 + r) * 64 + k] = f2bf(v);
        }
        return;
    }
    __shared__ __align__(16) float w1s[32 * 256];
    const int oc = blockIdx.x & 1;
    const int pc = blockIdx.x >> 1;
    for (int i = tid; i < 32 * 256; i += 256)
        w1s[i] = w1[oc * 32 * 256 + i];
    __syncthreads();

    const int pix = tid & 63, osel = tid >> 6;
    const int p = pc * 64 + pix;
    const int b = p / HWSZ, hw = p - b * HWSZ;
    const float* xp = x + (size_t)b * 256 * HWSZ + hw;

    float acc[8] = {0.f,0.f,0.f,0.f,0.f,0.f,0.f,0.f};
    #pragma unroll 4
    for (int c0 = 0; c0 < 256; c0 += 4) {
        float xv0 = xp[(size_t)(c0 + 0) * HWSZ];
        float xv1 = xp[(size_t)(c0 + 1) * HWSZ];
        float xv2 = xp[(size_t)(c0 + 2) * HWSZ];
        float xv3 = xp[(size_t)(c0 + 3) * HWSZ];
        #pragma unroll
        for (int j = 0; j < 8; ++j) {
            float4 wv = *(const float4*)&w1s[(osel * 8 + j) * 256 + c0];
            acc[j] += wv.x * xv0 + wv.y * xv1 + wv.z * xv2 + wv.w * xv3;
        }
    }
    const int o0 = oc * 32 + osel * 8;
    short8 sv;
    #pragma unroll
    for (int j = 0; j < 8; ++j) {
        int o = o0 + j;
        float sc = gamma[o] * rsqrtf(var[o] + 1e-5f);
        float sh = beta[o] - mean[o] * sc;
        float v = acc[j] * sc + sh;
        v = v > 0.f ? v : 0.f;
        sv[j] = (short)f2bf(v);
    }
    *(short8*)&t_bf[(size_t)p * 64 + o0] = sv;
}

// --------- Kernel B: MFMA weight-GEMM (2 groups) + reg-resident dynamic conv ---------
// grid 1792 = 8 group-pairs x 224 (b,h); block 256 (4 waves)
__global__ __launch_bounds__(256) void kb_fused(
    const float* __restrict__ y, const float* __restrict__ b2,
    const unsigned short* __restrict__ t_bf, const unsigned short* __restrict__ w2p,
    float* __restrict__ out)
{
    // wgt bf16 [2 groups][52 kk][68 px-stride]  (rows 8B-aligned: 136 B)
    __shared__ __align__(16) unsigned short wgt[2 * 52 * 68];

    const int tid = threadIdx.x;
    // XCD swizzle: gp = phys&7 -> each XCD owns one group-pair over contiguous (b,h)
    const int gp = blockIdx.x & 7;
    const int bh = blockIdx.x >> 3;            // 0..223
    const int b = bh / HH, h = bh - b * HH;

    // ---- phase 1: MFMA  wgt[g][kk][px] = sum_k t[px][k] * w2p[g][kk][k] + b2 ----
    {
        const int lane = tid & 63, wv = tid >> 6;
        const int m = lane & 15, q = lane >> 4;
        #pragma unroll
        for (int it = 0; it < 2; ++it) {
            const int tsk = wv + 4 * it;       // 0..7 = 2 groups x 4 pixel-tiles
            const int gl = tsk >> 2, pt = tsk & 3;
            const int g = gp * 2 + gl;
            const int prow = b * HWSZ + h * WW + pt * 16 + m;
            const short8* ta = (const short8*)(t_bf + (size_t)prow * 64 + q * 8);
            short8 a0 = ta[0];                 // k = q*8 + 0..7
            short8 a1 = ta[4];                 // k = 32 + q*8 + 0..7
            f32x4 acc[4];
            #pragma unroll
            for (int mt = 0; mt < 4; ++mt) { acc[mt][0]=0.f; acc[mt][1]=0.f; acc[mt][2]=0.f; acc[mt][3]=0.f; }
            #pragma unroll
            for (int mt = 0; mt < 4; ++mt) {
                const short8* tb = (const short8*)(w2p +
                    (size_t)(g * 64 + mt * 16 + m) * 64 + q * 8);
                short8 b0 = tb[0], b1 = tb[4];
                acc[mt] = __builtin_amdgcn_mfma_f32_16x16x32_bf16(a0, b0, acc[mt], 0, 0, 0);
                acc[mt] = __builtin_amdgcn_mfma_f32_16x16x32_bf16(a1, b1, acc[mt], 0, 0, 0);
            }
            // D: col(kk)=lane&15, row(px)=(lane>>4)*4+j
            #pragma unroll
            for (int mt = 0; mt < 4; ++mt) {
                const int kk = mt * 16 + m;
                if (kk < 52) {
                    float bv = (kk < KK) ? b2[g * KK + kk] : 0.f;
                    f32x4 v = acc[mt];
                    unsigned r0 = (unsigned)f2bf(v[0] + bv) | ((unsigned)f2bf(v[1] + bv) << 16);
                    unsigned r1 = (unsigned)f2bf(v[2] + bv) | ((unsigned)f2bf(v[3] + bv) << 16);
                    const int pxb = pt * 16 + q * 4;
                    *(uint2*)&wgt[(gl * 52 + kk) * 68 + pxb] = make_uint2(r0, r1);
                }
            }
        }
    }
    __syncthreads();

    // ---- phase 2: conv, thread = (gl, cc-pair, px-quad), y from global ----
    if (tid < 224) {
        const int gl = tid / 112;
        const int rem = tid - gl * 112;
        const int c2 = rem / 14, pq = rem - c2 * 14;
        const int g = gp * 2 + gl;
        const int cc0 = c2 * 2;
        const float* y0 = y + (size_t)(b * 256 + g * 16 + cc0) * HWSZ;
        const float* y1 = y0 + HWSZ;
        const unsigned short* wg = &wgt[gl * 52 * 68 + pq * 4];

        float a00=0.f,a01=0.f,a02=0.f,a03=0.f;
        float a10=0.f,a11=0.f,a12=0.f,a13=0.f;
        const float4 z4 = make_float4(0.f, 0.f, 0.f, 0.f);

        #pragma unroll
        for (int di = 0; di < KS; ++di) {
            const int hs = h - 3 + di;
            if (hs >= 0 && hs < HH) {          // block-uniform branch
                const int roff = hs * WW + pq * 4 - 4;
                float4 q00 = (pq > 0)  ? *(const float4*)(y0 + roff)     : z4;
                float4 q01 =             *(const float4*)(y0 + roff + 4);
                float4 q02 = (pq < 13) ? *(const float4*)(y0 + roff + 8) : z4;
                float4 q10 = (pq > 0)  ? *(const float4*)(y1 + roff)     : z4;
                float4 q11 =             *(const float4*)(y1 + roff + 4);
                float4 q12 = (pq < 13) ? *(const float4*)(y1 + roff + 8) : z4;
                float w0[12] = {q00.x,q00.y,q00.z,q00.w, q01.x,q01.y,q01.z,q01.w, q02.x,q02.y,q02.z,q02.w};
                float w1v[12]= {q10.x,q10.y,q10.z,q10.w, q11.x,q11.y,q11.z,q11.w, q12.x,q12.y,q12.z,q12.w};
                #pragma unroll
                for (int dj = 0; dj < KS; ++dj) {
                    uint2 wr = *(const uint2*)&wg[(di * KS + dj) * 68];
                    float g0 = bflo(wr.x), g1 = bfhi(wr.x);
                    float g2 = bflo(wr.y), g3 = bfhi(wr.y);
                    a00 += g0 * w0[dj + 1];  a01 += g1 * w0[dj + 2];
                    a02 += g2 * w0[dj + 3];  a03 += g3 * w0[dj + 4];
                    a10 += g0 * w1v[dj + 1]; a11 += g1 * w1v[dj + 2];
                    a12 += g2 * w1v[dj + 3]; a13 += g3 * w1v[dj + 4];
                }
            }
        }
        float* o0 = out + (size_t)(b * 256 + g * 16 + cc0) * HWSZ + h * WW + pq * 4;
        *(float4*)o0 = make_float4(a00, a01, a02, a03);
        *(float4*)(o0 + HWSZ) = make_float4(a10, a11, a12, a13);
    }
}

extern "C" void kernel_launch(void* const* d_in, const int* in_sizes, int n_in,
                              void* d_out, int out_size, void* d_ws, size_t ws_size,
                              hipStream_t stream) {
    const float* x     = (const float*)d_in[0];
    const float* y     = (const float*)d_in[1];
    const float* w1    = (const float*)d_in[2];
    const float* gamma = (const float*)d_in[3];
    const float* beta  = (const float*)d_in[4];
    const float* mean  = (const float*)d_in[5];
    const float* var   = (const float*)d_in[6];
    const float* w2    = (const float*)d_in[7];
    const float* b2    = (const float*)d_in[8];
    float* out = (float*)d_out;

    unsigned short* t_bf = (unsigned short*)d_ws;          // [12608][64] bf16
    unsigned short* w2p  = t_bf + (size_t)12608 * 64;      // [16*64][64] bf16

    ka_tmid<<<408, 256, 0, stream>>>(x, w1, gamma, beta, mean, var, w2, t_bf, w2p);
    kb_fused<<<1792, 256, 0, stream>>>(y, b2, t_bf, w2p, out);
}